// Round 6
// baseline (571.697 us; speedup 1.0000x reference)
//
#include <hip/hip_runtime.h>
#include <stdint.h>

// Periodic radius-graph neighbor list (AlphaNet). B=16, N=256, C=27, M=6912.
// R6 = MEASUREMENT ROUND: the R4 fused kernel executed TWICE per launch
// (idempotent; nn re-zeroed between runs). dur = baseline + 2*ours, and with
// R4's dur = baseline + ours known (467 us), this yields ours exactly.
// Kernel body is byte-identical to R4.

constexpr int B_ = 16, N_ = 256, C_ = 27;
constexpr int M_ = N_ * C_;      // 6912
constexpr int MAXC = 256;        // candidate slots; mean ~78
constexpr int KMAX = 32;

__global__ __launch_bounds__(256)
void nbr_kernel(const float* __restrict__ pos,    // [B,N,3]
                const float* __restrict__ cell,   // [B,3,3]
                float* __restrict__ dist,         // [B,N,M]
                float* __restrict__ dvec,         // [B,N,M,3]
                float* __restrict__ nn)           // [B] (float counts, pre-zeroed)
{
#pragma clang fp contract(off)
    __shared__ float offx[C_], offy[C_], offz[C_];
    __shared__ unsigned long long keys[MAXC];
    __shared__ float4 vals[MAXC];               // dx,dy,dz,dsq
    __shared__ float4 kept[KMAX];               // dx,dy,dz,dist (by rank)
    __shared__ unsigned char slot[M_];          // 0 = empty, else rank+1
    __shared__ int cnt;

    const int bi  = blockIdx.x;   // b*N + i
    const int b   = bi >> 8;
    const int i   = bi & 255;
    const int tid = threadIdx.x;

    const float* pb = pos + b * N_ * 3;
    const float pjx = pb[tid * 3 + 0], pjy = pb[tid * 3 + 1], pjz = pb[tid * 3 + 2];
    const float pix = pb[i * 3 + 0],   piy = pb[i * 3 + 1],   piz = pb[i * 3 + 2];

    if (tid < C_) {
        const float n1 = (float)(tid / 9 - 1);
        const float n2 = (float)((tid / 3) % 3 - 1);
        const float n3 = (float)(tid % 3 - 1);
        const float* cb = cell + b * 9;
        offx[tid] = n1 * cb[0] + n2 * cb[3] + n3 * cb[6];
        offy[tid] = n1 * cb[1] + n2 * cb[4] + n3 * cb[7];
        offz[tid] = n1 * cb[2] + n2 * cb[5] + n3 * cb[8];
    }
    uint32_t* slot32 = (uint32_t*)slot;
    for (int w = tid; w < M_ / 4; w += 256) slot32[w] = 0;
    if (tid == 0) cnt = 0;
    __syncthreads();

    // pass 1: bit-exact numpy order: s = pj + off; d = pi - s; ((dx*dx+dy*dy)+dz*dz)
    #pragma unroll 1
    for (int c = 0; c < C_; ++c) {
        const float sx = pjx + offx[c], sy = pjy + offy[c], sz = pjz + offz[c];
        const float dx = pix - sx, dy = piy - sy, dz = piz - sz;
        const float dsq = dx * dx + dy * dy + dz * dz;
        if (dsq <= 25.0f && dsq > 1e-4f) {
            const int idx = atomicAdd(&cnt, 1);              // LDS atomic
            if (idx < MAXC) {
                keys[idx] = ((unsigned long long)__float_as_uint(dsq) << 32)
                          | (unsigned)(tid * C_ + c);
                vals[idx] = make_float4(dx, dy, dz, dsq);
            }
        }
    }
    __syncthreads();

    int K = cnt; if (K > MAXC) K = MAXC;
    if (tid == 0)
        atomicAdd(&nn[b], (float)(K < KMAX ? K : KMAX));

    for (int idx = tid; idx < K; idx += 256) {
        const unsigned long long key = keys[idx];
        int r = 0;
        for (int q = 0; q < K; ++q) r += (keys[q] < key) ? 1 : 0;
        if (r < KMAX) {
            const int m = (int)(key & 0xffffffffu);
            const float4 v = vals[idx];
            kept[r] = make_float4(v.x, v.y, v.z, sqrtf(v.w));
            slot[m] = (unsigned char)(r + 1);
        }
    }
    __syncthreads();

    float4* dp = (float4*)(dist + (size_t)bi * M_);
    float4* vp = (float4*)(dvec + (size_t)bi * (size_t)(M_ * 3));

    for (int g = tid; g < M_ / 4; g += 256) {
        float4 out = make_float4(0.f, 0.f, 0.f, 0.f);
        const uint32_t s4 = slot32[g];
        if (s4) {
            #pragma unroll
            for (int u = 0; u < 4; ++u) {
                const uint32_t s = (s4 >> (8 * u)) & 0xffu;
                if (s) (&out.x)[u] = kept[s - 1].w;
            }
        }
        dp[g] = out;
    }
    for (int h = tid; h < 3 * M_ / 4; h += 256) {
        const int e0 = 4 * h;
        const int m0 = e0 / 3;
        const int m1 = (e0 + 3) / 3;
        float4 out = make_float4(0.f, 0.f, 0.f, 0.f);
        if ((slot[m0] | slot[m1]) != 0) {
            #pragma unroll
            for (int u = 0; u < 4; ++u) {
                const int e = e0 + u;
                const int m = e / 3;
                const int d = e - 3 * m;
                const uint32_t s = slot[m];
                if (s) (&out.x)[u] = (&kept[s - 1].x)[d];
            }
        }
        vp[h] = out;
    }
}

extern "C" void kernel_launch(void* const* d_in, const int* in_sizes, int n_in,
                              void* d_out, int out_size, void* d_ws, size_t ws_size,
                              hipStream_t stream)
{
    const float* pos  = (const float*)d_in[0];
    const float* cell = (const float*)d_in[1];
    float* dist = (float*)d_out;
    float* dvec = dist + (size_t)B_ * N_ * M_;
    float* nn   = dvec + (size_t)B_ * N_ * M_ * 3;

    // run 1
    hipMemsetAsync(nn, 0, B_ * sizeof(float), stream);
    nbr_kernel<<<dim3(B_ * N_), dim3(256), 0, stream>>>(pos, cell, dist, dvec, nn);
    // run 2 (identical work; nn re-zeroed so final output is unchanged)
    hipMemsetAsync(nn, 0, B_ * sizeof(float), stream);
    nbr_kernel<<<dim3(B_ * N_), dim3(256), 0, stream>>>(pos, cell, dist, dvec, nn);
}

// Round 8
// 467.511 us; speedup vs baseline: 1.2229x; 1.2229x over previous
//
#include <hip/hip_runtime.h>
#include <stdint.h>

// Periodic radius-graph neighbor list (AlphaNet). B=16, N=256, C=27, M=6912.
// Outputs (flat f32 concat): dist [B,N,M], dvec [B,N,M,3], num_neighbors_image [B].
// keep = (1e-4 < dsqr <= 25) AND stable-sort rank < 32
//      == key (f32bits(dsqr)<<32 | m) among the 32 smallest within-radius keys.
//
// R8 = R4 fused kernel + non-temporal output stores (nt cache policy, like
// rocclr's 6.1 TB/s fillBuffer) to avoid L2 write-allocate/dirty-eviction
// thrash on the 453 MB write-once stream. (R7 retry: clang's nontemporal
// builtin needs a native vector type, not HIP_vector_type float4.)
// Measured R4 kernel time: ~105 us (4.3 TB/s). Floor: ~72 us (6.3 TB/s).

constexpr int B_ = 16, N_ = 256, C_ = 27;
constexpr int M_ = N_ * C_;      // 6912
constexpr int MAXC = 256;        // candidate slots; mean ~78
constexpr int KMAX = 32;

typedef float vfloat4 __attribute__((ext_vector_type(4)));

__device__ __forceinline__ void nt_store4(float* p, float a, float b, float c, float d) {
    vfloat4 v; v.x = a; v.y = b; v.z = c; v.w = d;
    __builtin_nontemporal_store(v, (vfloat4*)p);
}

__global__ __launch_bounds__(256)
void nbr_kernel(const float* __restrict__ pos,    // [B,N,3]
                const float* __restrict__ cell,   // [B,3,3]
                float* __restrict__ dist,         // [B,N,M]
                float* __restrict__ dvec,         // [B,N,M,3]
                float* __restrict__ nn)           // [B] (float counts, pre-zeroed)
{
#pragma clang fp contract(off)
    __shared__ float offx[C_], offy[C_], offz[C_];
    __shared__ unsigned long long keys[MAXC];
    __shared__ float4 vals[MAXC];               // dx,dy,dz,dsq
    __shared__ float4 kept[KMAX];               // dx,dy,dz,dist (by rank)
    __shared__ unsigned char slot[M_];          // 0 = empty, else rank+1
    __shared__ int cnt;

    const int bi  = blockIdx.x;   // b*N + i
    const int b   = bi >> 8;
    const int i   = bi & 255;
    const int tid = threadIdx.x;

    const float* pb = pos + b * N_ * 3;
    const float pjx = pb[tid * 3 + 0], pjy = pb[tid * 3 + 1], pjz = pb[tid * 3 + 2];
    const float pix = pb[i * 3 + 0],   piy = pb[i * 3 + 1],   piz = pb[i * 3 + 2];

    if (tid < C_) {
        const float n1 = (float)(tid / 9 - 1);
        const float n2 = (float)((tid / 3) % 3 - 1);
        const float n3 = (float)(tid % 3 - 1);
        const float* cb = cell + b * 9;
        offx[tid] = n1 * cb[0] + n2 * cb[3] + n3 * cb[6];
        offy[tid] = n1 * cb[1] + n2 * cb[4] + n3 * cb[7];
        offz[tid] = n1 * cb[2] + n2 * cb[5] + n3 * cb[8];
    }
    uint32_t* slot32 = (uint32_t*)slot;
    for (int w = tid; w < M_ / 4; w += 256) slot32[w] = 0;
    if (tid == 0) cnt = 0;
    __syncthreads();

    // pass 1: bit-exact numpy order: s = pj + off; d = pi - s; ((dx*dx+dy*dy)+dz*dz)
    #pragma unroll 1
    for (int c = 0; c < C_; ++c) {
        const float sx = pjx + offx[c], sy = pjy + offy[c], sz = pjz + offz[c];
        const float dx = pix - sx, dy = piy - sy, dz = piz - sz;
        const float dsq = dx * dx + dy * dy + dz * dz;
        if (dsq <= 25.0f && dsq > 1e-4f) {
            const int idx = atomicAdd(&cnt, 1);              // LDS atomic
            if (idx < MAXC) {
                keys[idx] = ((unsigned long long)__float_as_uint(dsq) << 32)
                          | (unsigned)(tid * C_ + c);
                vals[idx] = make_float4(dx, dy, dz, dsq);
            }
        }
    }
    __syncthreads();

    int K = cnt; if (K > MAXC) K = MAXC;
    if (tid == 0)
        atomicAdd(&nn[b], (float)(K < KMAX ? K : KMAX));

    for (int idx = tid; idx < K; idx += 256) {
        const unsigned long long key = keys[idx];
        int r = 0;
        for (int q = 0; q < K; ++q) r += (keys[q] < key) ? 1 : 0;
        if (r < KMAX) {
            const int m = (int)(key & 0xffffffffu);
            const float4 v = vals[idx];
            kept[r] = make_float4(v.x, v.y, v.z, sqrtf(v.w));
            slot[m] = (unsigned char)(r + 1);
        }
    }
    __syncthreads();

    float* drow = dist + (size_t)bi * M_;
    float* vrow = dvec + (size_t)bi * (size_t)(M_ * 3);

    // merged fill, dist region: 1728 float4 groups; each stored exactly once (nt)
    for (int g = tid; g < M_ / 4; g += 256) {
        float o0 = 0.f, o1 = 0.f, o2 = 0.f, o3 = 0.f;
        const uint32_t s4 = slot32[g];
        if (s4) {
            uint32_t s;
            s = s4 & 0xffu;         if (s) o0 = kept[s - 1].w;
            s = (s4 >> 8) & 0xffu;  if (s) o1 = kept[s - 1].w;
            s = (s4 >> 16) & 0xffu; if (s) o2 = kept[s - 1].w;
            s = (s4 >> 24) & 0xffu; if (s) o3 = kept[s - 1].w;
        }
        nt_store4(drow + 4 * g, o0, o1, o2, o3);
    }
    // merged fill, dvec region: 5184 float4 groups
    for (int h = tid; h < 3 * M_ / 4; h += 256) {
        const int e0 = 4 * h;
        const int m0 = e0 / 3;
        const int m1 = (e0 + 3) / 3;
        float o[4] = {0.f, 0.f, 0.f, 0.f};
        if ((slot[m0] | slot[m1]) != 0) {
            #pragma unroll
            for (int u = 0; u < 4; ++u) {
                const int e = e0 + u;
                const int m = e / 3;
                const int d = e - 3 * m;
                const uint32_t s = slot[m];
                if (s) o[u] = (&kept[s - 1].x)[d];
            }
        }
        nt_store4(vrow + e0, o[0], o[1], o[2], o[3]);
    }
}

extern "C" void kernel_launch(void* const* d_in, const int* in_sizes, int n_in,
                              void* d_out, int out_size, void* d_ws, size_t ws_size,
                              hipStream_t stream)
{
    const float* pos  = (const float*)d_in[0];
    const float* cell = (const float*)d_in[1];
    float* dist = (float*)d_out;
    float* dvec = dist + (size_t)B_ * N_ * M_;
    float* nn   = dvec + (size_t)B_ * N_ * M_ * 3;
    (void)hipMemsetAsync(nn, 0, B_ * sizeof(float), stream);   // zero count tail only
    nbr_kernel<<<dim3(B_ * N_), dim3(256), 0, stream>>>(pos, cell, dist, dvec, nn);
}

// Round 9
// 465.655 us; speedup vs baseline: 1.2277x; 1.0040x over previous
//
#include <hip/hip_runtime.h>
#include <stdint.h>

// Periodic radius-graph neighbor list (AlphaNet). B=16, N=256, C=27, M=6912.
// Outputs (flat f32 concat): dist [B,N,M], dvec [B,N,M,3], num_neighbors_image [B].
// keep = (1e-4 < dsqr <= 25) AND stable-sort rank < 32
//      == key (f32bits(dsqr)<<32 | m) among the 32 smallest within-radius keys.
//
// R9 = R4 fused kernel, store loops restructured into bursts of 4 back-to-back
// float4 nt stores per thread (memcpy-style unroll) to deepen per-channel MC
// queues. Timing model (locked vs R3/R5/R6): dur = 363 us poison + ours.
// ours(R4/R8) ~105 us = 4.3 TB/s; rocclr fill proves 6.2 TB/s pure writes.

constexpr int B_ = 16, N_ = 256, C_ = 27;
constexpr int M_ = N_ * C_;      // 6912
constexpr int MAXC = 256;        // candidate slots; mean ~78
constexpr int KMAX = 32;

typedef float vfloat4 __attribute__((ext_vector_type(4)));

__device__ __forceinline__ void nt_store4(float* p, float a, float b, float c, float d) {
    vfloat4 v; v.x = a; v.y = b; v.z = c; v.w = d;
    __builtin_nontemporal_store(v, (vfloat4*)p);
}

__global__ __launch_bounds__(256)
void nbr_kernel(const float* __restrict__ pos,    // [B,N,3]
                const float* __restrict__ cell,   // [B,3,3]
                float* __restrict__ dist,         // [B,N,M]
                float* __restrict__ dvec,         // [B,N,M,3]
                float* __restrict__ nn)           // [B] (float counts, pre-zeroed)
{
#pragma clang fp contract(off)
    __shared__ float offx[C_], offy[C_], offz[C_];
    __shared__ unsigned long long keys[MAXC];
    __shared__ float4 vals[MAXC];               // dx,dy,dz,dsq
    __shared__ float4 kept[KMAX];               // dx,dy,dz,dist (by rank)
    __shared__ unsigned char slot[M_];          // 0 = empty, else rank+1
    __shared__ int cnt;

    const int bi  = blockIdx.x;   // b*N + i
    const int b   = bi >> 8;
    const int i   = bi & 255;
    const int tid = threadIdx.x;

    const float* pb = pos + b * N_ * 3;
    const float pjx = pb[tid * 3 + 0], pjy = pb[tid * 3 + 1], pjz = pb[tid * 3 + 2];
    const float pix = pb[i * 3 + 0],   piy = pb[i * 3 + 1],   piz = pb[i * 3 + 2];

    if (tid < C_) {
        const float n1 = (float)(tid / 9 - 1);
        const float n2 = (float)((tid / 3) % 3 - 1);
        const float n3 = (float)(tid % 3 - 1);
        const float* cb = cell + b * 9;
        offx[tid] = n1 * cb[0] + n2 * cb[3] + n3 * cb[6];
        offy[tid] = n1 * cb[1] + n2 * cb[4] + n3 * cb[7];
        offz[tid] = n1 * cb[2] + n2 * cb[5] + n3 * cb[8];
    }
    uint32_t* slot32 = (uint32_t*)slot;
    for (int w = tid; w < M_ / 4; w += 256) slot32[w] = 0;
    if (tid == 0) cnt = 0;
    __syncthreads();

    // pass 1: bit-exact numpy order: s = pj + off; d = pi - s; ((dx*dx+dy*dy)+dz*dz)
    #pragma unroll 1
    for (int c = 0; c < C_; ++c) {
        const float sx = pjx + offx[c], sy = pjy + offy[c], sz = pjz + offz[c];
        const float dx = pix - sx, dy = piy - sy, dz = piz - sz;
        const float dsq = dx * dx + dy * dy + dz * dz;
        if (dsq <= 25.0f && dsq > 1e-4f) {
            const int idx = atomicAdd(&cnt, 1);              // LDS atomic
            if (idx < MAXC) {
                keys[idx] = ((unsigned long long)__float_as_uint(dsq) << 32)
                          | (unsigned)(tid * C_ + c);
                vals[idx] = make_float4(dx, dy, dz, dsq);
            }
        }
    }
    __syncthreads();

    int K = cnt; if (K > MAXC) K = MAXC;
    if (tid == 0)
        atomicAdd(&nn[b], (float)(K < KMAX ? K : KMAX));

    for (int idx = tid; idx < K; idx += 256) {
        const unsigned long long key = keys[idx];
        int r = 0;
        for (int q = 0; q < K; ++q) r += (keys[q] < key) ? 1 : 0;
        if (r < KMAX) {
            const int m = (int)(key & 0xffffffffu);
            const float4 v = vals[idx];
            kept[r] = make_float4(v.x, v.y, v.z, sqrtf(v.w));
            slot[m] = (unsigned char)(r + 1);
        }
    }
    __syncthreads();

    float* drow = dist + (size_t)bi * M_;
    float* vrow = dvec + (size_t)bi * (size_t)(M_ * 3);

    // ---- dist region: 1728 float4 groups = 1 burst of 4 + 2 singles + tail(192)
    {
        float o[4][4];
        #pragma unroll
        for (int k = 0; k < 4; ++k) {
            const int g = tid + k * 256;
            o[k][0] = o[k][1] = o[k][2] = o[k][3] = 0.f;
            const uint32_t s4 = slot32[g];
            if (s4) {
                uint32_t s;
                s = s4 & 0xffu;         if (s) o[k][0] = kept[s - 1].w;
                s = (s4 >> 8) & 0xffu;  if (s) o[k][1] = kept[s - 1].w;
                s = (s4 >> 16) & 0xffu; if (s) o[k][2] = kept[s - 1].w;
                s = (s4 >> 24) & 0xffu; if (s) o[k][3] = kept[s - 1].w;
            }
        }
        #pragma unroll
        for (int k = 0; k < 4; ++k)
            nt_store4(drow + 4 * (tid + k * 256), o[k][0], o[k][1], o[k][2], o[k][3]);
    }
    #pragma unroll
    for (int k = 4; k < 6; ++k) {
        const int g = tid + k * 256;
        float o0 = 0.f, o1 = 0.f, o2 = 0.f, o3 = 0.f;
        const uint32_t s4 = slot32[g];
        if (s4) {
            uint32_t s;
            s = s4 & 0xffu;         if (s) o0 = kept[s - 1].w;
            s = (s4 >> 8) & 0xffu;  if (s) o1 = kept[s - 1].w;
            s = (s4 >> 16) & 0xffu; if (s) o2 = kept[s - 1].w;
            s = (s4 >> 24) & 0xffu; if (s) o3 = kept[s - 1].w;
        }
        nt_store4(drow + 4 * g, o0, o1, o2, o3);
    }
    if (tid < 192) {
        const int g = 1536 + tid;
        float o0 = 0.f, o1 = 0.f, o2 = 0.f, o3 = 0.f;
        const uint32_t s4 = slot32[g];
        if (s4) {
            uint32_t s;
            s = s4 & 0xffu;         if (s) o0 = kept[s - 1].w;
            s = (s4 >> 8) & 0xffu;  if (s) o1 = kept[s - 1].w;
            s = (s4 >> 16) & 0xffu; if (s) o2 = kept[s - 1].w;
            s = (s4 >> 24) & 0xffu; if (s) o3 = kept[s - 1].w;
        }
        nt_store4(drow + 4 * g, o0, o1, o2, o3);
    }

    // ---- dvec region: 5184 float4 groups = 5 bursts of 4 + tail(64)
    #pragma unroll 1
    for (int it = 0; it < 5; ++it) {
        const int hbase = it * 1024 + tid;
        float o[4][4];
        #pragma unroll
        for (int k = 0; k < 4; ++k) {
            const int h = hbase + k * 256;
            const int e0 = 4 * h;
            const int m0 = e0 / 3;
            const int m1 = (e0 + 3) / 3;
            o[k][0] = o[k][1] = o[k][2] = o[k][3] = 0.f;
            if ((slot[m0] | slot[m1]) != 0) {
                #pragma unroll
                for (int u = 0; u < 4; ++u) {
                    const int e = e0 + u;
                    const int m = e / 3;
                    const int d = e - 3 * m;
                    const uint32_t s = slot[m];
                    if (s) o[k][u] = (&kept[s - 1].x)[d];
                }
            }
        }
        #pragma unroll
        for (int k = 0; k < 4; ++k)
            nt_store4(vrow + 4 * (hbase + k * 256), o[k][0], o[k][1], o[k][2], o[k][3]);
    }
    if (tid < 64) {
        const int h = 5120 + tid;
        const int e0 = 4 * h;
        const int m0 = e0 / 3;
        const int m1 = (e0 + 3) / 3;
        float o0 = 0.f, o1 = 0.f, o2 = 0.f, o3 = 0.f;
        if ((slot[m0] | slot[m1]) != 0) {
            float oo[4] = {0.f, 0.f, 0.f, 0.f};
            #pragma unroll
            for (int u = 0; u < 4; ++u) {
                const int e = e0 + u;
                const int m = e / 3;
                const int d = e - 3 * m;
                const uint32_t s = slot[m];
                if (s) oo[u] = (&kept[s - 1].x)[d];
            }
            o0 = oo[0]; o1 = oo[1]; o2 = oo[2]; o3 = oo[3];
        }
        nt_store4(vrow + e0, o0, o1, o2, o3);
    }
}

extern "C" void kernel_launch(void* const* d_in, const int* in_sizes, int n_in,
                              void* d_out, int out_size, void* d_ws, size_t ws_size,
                              hipStream_t stream)
{
    const float* pos  = (const float*)d_in[0];
    const float* cell = (const float*)d_in[1];
    float* dist = (float*)d_out;
    float* dvec = dist + (size_t)B_ * N_ * M_;
    float* nn   = dvec + (size_t)B_ * N_ * M_ * 3;
    (void)hipMemsetAsync(nn, 0, B_ * sizeof(float), stream);   // zero count tail only
    nbr_kernel<<<dim3(B_ * N_), dim3(256), 0, stream>>>(pos, cell, dist, dvec, nn);
}